// Round 1
// baseline (448.366 us; speedup 1.0000x reference)
//
#include <hip/hip_runtime.h>

// out[b] = E @ x[b], E = exp_se3(w, v, theta) (4x4, uniform over batch).
// Memory-bound streamer: 256 MiB in + 256 MiB out.

__global__ __launch_bounds__(256) void se3_apply_kernel(
    const float* __restrict__ w3,
    const float* __restrict__ v3,
    const float* __restrict__ th1,
    const float* __restrict__ x,
    float* __restrict__ out,
    int B)
{
    // ---- Compute E (wave-uniform; scalar-load friendly) ----
    const float wx = w3[0], wy = w3[1], wz = w3[2];
    const float vx = v3[0], vy = v3[1], vz = v3[2];
    const float th = th1[0];
    const float s = sinf(th);
    const float c = cosf(th);
    const float a = 1.0f - c;       // coeff on W in R, on W in V
    const float bq = th - s;        // coeff on W2 in V

    // W and W2 entries
    const float W00 = 0.f,  W01 = -wz, W02 =  wy;
    const float W10 =  wz,  W11 = 0.f, W12 = -wx;
    const float W20 = -wy,  W21 =  wx, W22 = 0.f;

    const float Q00 = -(wy*wy + wz*wz), Q01 = wx*wy,            Q02 = wx*wz;
    const float Q10 = wx*wy,            Q11 = -(wx*wx + wz*wz), Q12 = wy*wz;
    const float Q20 = wx*wz,            Q21 = wy*wz,            Q22 = -(wx*wx + wy*wy);

    // R = I + s*W + (1-c)*W2
    const float R00 = 1.0f + s*W00 + a*Q00;
    const float R01 =        s*W01 + a*Q01;
    const float R02 =        s*W02 + a*Q02;
    const float R10 =        s*W10 + a*Q10;
    const float R11 = 1.0f + s*W11 + a*Q11;
    const float R12 =        s*W12 + a*Q12;
    const float R20 =        s*W20 + a*Q20;
    const float R21 =        s*W21 + a*Q21;
    const float R22 = 1.0f + s*W22 + a*Q22;

    // V = theta*I + (1-c)*W + (theta-s)*W2 ; t = V @ v
    const float V00 = th   + a*W00 + bq*Q00;
    const float V01 =        a*W01 + bq*Q01;
    const float V02 =        a*W02 + bq*Q02;
    const float V10 =        a*W10 + bq*Q10;
    const float V11 = th   + a*W11 + bq*Q11;
    const float V12 =        a*W12 + bq*Q12;
    const float V20 =        a*W20 + bq*Q20;
    const float V21 =        a*W21 + bq*Q21;
    const float V22 = th   + a*W22 + bq*Q22;

    const float t0 = V00*vx + V01*vy + V02*vz;
    const float t1 = V10*vx + V11*vy + V12*vz;
    const float t2 = V20*vx + V21*vy + V22*vz;

    // ---- Per-batch 4x4 transform ----
    const int b = blockIdx.x * blockDim.x + threadIdx.x;
    if (b >= B) return;

    const float4* __restrict__ xv = reinterpret_cast<const float4*>(x) + (size_t)b * 4;
    float4* __restrict__ ov       = reinterpret_cast<float4*>(out)      + (size_t)b * 4;

    const float4 r0 = xv[0];
    const float4 r1 = xv[1];
    const float4 r2 = xv[2];
    const float4 r3 = xv[3];

    float4 o0, o1, o2;
    o0.x = R00*r0.x + R01*r1.x + R02*r2.x + t0*r3.x;
    o0.y = R00*r0.y + R01*r1.y + R02*r2.y + t0*r3.y;
    o0.z = R00*r0.z + R01*r1.z + R02*r2.z + t0*r3.z;
    o0.w = R00*r0.w + R01*r1.w + R02*r2.w + t0*r3.w;

    o1.x = R10*r0.x + R11*r1.x + R12*r2.x + t1*r3.x;
    o1.y = R10*r0.y + R11*r1.y + R12*r2.y + t1*r3.y;
    o1.z = R10*r0.z + R11*r1.z + R12*r2.z + t1*r3.z;
    o1.w = R10*r0.w + R11*r1.w + R12*r2.w + t1*r3.w;

    o2.x = R20*r0.x + R21*r1.x + R22*r2.x + t2*r3.x;
    o2.y = R20*r0.y + R21*r1.y + R22*r2.y + t2*r3.y;
    o2.z = R20*r0.z + R21*r1.z + R22*r2.z + t2*r3.z;
    o2.w = R20*r0.w + R21*r1.w + R22*r2.w + t2*r3.w;

    ov[0] = o0;
    ov[1] = o1;
    ov[2] = o2;
    ov[3] = r3;   // bottom row of E is [0,0,0,1] -> pass-through
}

extern "C" void kernel_launch(void* const* d_in, const int* in_sizes, int n_in,
                              void* d_out, int out_size, void* d_ws, size_t ws_size,
                              hipStream_t stream) {
    const float* w  = (const float*)d_in[0];
    const float* v  = (const float*)d_in[1];
    const float* th = (const float*)d_in[2];
    const float* x  = (const float*)d_in[3];
    float* out = (float*)d_out;

    const int B = in_sizes[3] / 16;   // 4x4 per batch element
    const int block = 256;
    const int grid = (B + block - 1) / block;
    se3_apply_kernel<<<grid, block, 0, stream>>>(w, v, th, x, out, B);
}

// Round 2
// 416.740 us; speedup vs baseline: 1.0759x; 1.0759x over previous
//
#include <hip/hip_runtime.h>

// out[b] = E @ x[b], E = exp_se3(w, v, theta) (4x4, uniform over batch).
// Row-parallel mapping: one lane per 16B matrix row -> fully coalesced
// loads/stores; rows of each matrix redistributed via __shfl within the
// aligned 4-lane cluster.

__global__ __launch_bounds__(256) void se3_apply_rows(
    const float* __restrict__ w3,
    const float* __restrict__ v3,
    const float* __restrict__ th1,
    const float* __restrict__ x,
    float* __restrict__ out,
    int NR)   // number of float4 rows = B*4
{
    // ---- Compute E (uniform) ----
    const float wx = w3[0], wy = w3[1], wz = w3[2];
    const float vx = v3[0], vy = v3[1], vz = v3[2];
    const float th = th1[0];
    const float s = sinf(th);
    const float c = cosf(th);
    const float a = 1.0f - c;
    const float bq = th - s;

    const float W01 = -wz, W02 =  wy;
    const float W10 =  wz, W12 = -wx;
    const float W20 = -wy, W21 =  wx;

    const float Q00 = -(wy*wy + wz*wz), Q01 = wx*wy,            Q02 = wx*wz;
    const float Q10 = wx*wy,            Q11 = -(wx*wx + wz*wz), Q12 = wy*wz;
    const float Q20 = wx*wz,            Q21 = wy*wz,            Q22 = -(wx*wx + wy*wy);

    // R = I + s*W + (1-c)*W2
    const float R00 = 1.0f + a*Q00;
    const float R01 =        s*W01 + a*Q01;
    const float R02 =        s*W02 + a*Q02;
    const float R10 =        s*W10 + a*Q10;
    const float R11 = 1.0f + a*Q11;
    const float R12 =        s*W12 + a*Q12;
    const float R20 =        s*W20 + a*Q20;
    const float R21 =        s*W21 + a*Q21;
    const float R22 = 1.0f + a*Q22;

    // V = theta*I + (1-c)*W + (theta-s)*W2 ; t = V @ v
    const float V00 = th   + bq*Q00;
    const float V01 =        a*W01 + bq*Q01;
    const float V02 =        a*W02 + bq*Q02;
    const float V10 =        a*W10 + bq*Q10;
    const float V11 = th   + bq*Q11;
    const float V12 =        a*W12 + bq*Q12;
    const float V20 =        a*W20 + bq*Q20;
    const float V21 =        a*W21 + bq*Q21;
    const float V22 = th   + bq*Q22;

    const float t0 = V00*vx + V01*vy + V02*vz;
    const float t1 = V10*vx + V11*vy + V12*vz;
    const float t2 = V20*vx + V21*vy + V22*vz;

    const int g = blockIdx.x * 256 + threadIdx.x;   // global row index
    if (g >= NR) return;

    const int lane = threadIdx.x & 63;
    const int i = lane & 3;                 // which output row this lane produces
    const int cluster = lane & ~3;          // base lane of this matrix's 4-lane cluster

    // Per-lane coefficients c_j = E[i][j]  (E row 3 = [0,0,0,1])
    const float c0 = (i == 0) ? R00 : (i == 1) ? R10 : (i == 2) ? R20 : 0.0f;
    const float c1 = (i == 0) ? R01 : (i == 1) ? R11 : (i == 2) ? R21 : 0.0f;
    const float c2 = (i == 0) ? R02 : (i == 1) ? R12 : (i == 2) ? R22 : 0.0f;
    const float c3 = (i == 0) ? t0  : (i == 1) ? t1  : (i == 2) ? t2  : 1.0f;

    // Coalesced load: lane ℓ reads row g (consecutive 16B)
    const float4 r = reinterpret_cast<const float4*>(x)[g];

    // Gather all 4 rows of my matrix from my 4-lane cluster
    float4 q0, q1, q2, q3;
    q0.x = __shfl(r.x, cluster + 0); q0.y = __shfl(r.y, cluster + 0);
    q0.z = __shfl(r.z, cluster + 0); q0.w = __shfl(r.w, cluster + 0);
    q1.x = __shfl(r.x, cluster + 1); q1.y = __shfl(r.y, cluster + 1);
    q1.z = __shfl(r.z, cluster + 1); q1.w = __shfl(r.w, cluster + 1);
    q2.x = __shfl(r.x, cluster + 2); q2.y = __shfl(r.y, cluster + 2);
    q2.z = __shfl(r.z, cluster + 2); q2.w = __shfl(r.w, cluster + 2);
    q3.x = __shfl(r.x, cluster + 3); q3.y = __shfl(r.y, cluster + 3);
    q3.z = __shfl(r.z, cluster + 3); q3.w = __shfl(r.w, cluster + 3);

    float4 o;
    o.x = c0*q0.x + c1*q1.x + c2*q2.x + c3*q3.x;
    o.y = c0*q0.y + c1*q1.y + c2*q2.y + c3*q3.y;
    o.z = c0*q0.z + c1*q1.z + c2*q2.z + c3*q3.z;
    o.w = c0*q0.w + c1*q1.w + c2*q2.w + c3*q3.w;

    // Coalesced store
    reinterpret_cast<float4*>(out)[g] = o;
}

extern "C" void kernel_launch(void* const* d_in, const int* in_sizes, int n_in,
                              void* d_out, int out_size, void* d_ws, size_t ws_size,
                              hipStream_t stream) {
    const float* w  = (const float*)d_in[0];
    const float* v  = (const float*)d_in[1];
    const float* th = (const float*)d_in[2];
    const float* x  = (const float*)d_in[3];
    float* out = (float*)d_out;

    const int NR = in_sizes[3] / 4;   // number of float4 rows = B*4
    const int block = 256;
    const int grid = (NR + block - 1) / block;
    se3_apply_rows<<<grid, block, 0, stream>>>(w, v, th, x, out, NR);
}